// Round 1
// baseline (2108.299 us; speedup 1.0000x reference)
//
#include <hip/hip_runtime.h>
#include <stdint.h>

// ============================ problem constants ============================
constexpr int VOC  = 50257;
constexpr int VPAD = 50304;          // VOC padded up to a multiple of 128
constexpr int DEMB = 768;
constexpr int NQ   = 4096;           // B*T
constexpr float EPS_HALF = 0.05f;    // EPSILON / 2

// 1 = jax threefry_partitionable (default in modern JAX): bits = o0^o1 of (0, idx)
// 0 = legacy split-iota mode: idx<h -> out0 of (idx, idx+h), else out1 of (idx-h, idx)
#define GUMBEL_MODE 1

typedef __attribute__((ext_vector_type(4))) short    short4_t;
typedef __attribute__((ext_vector_type(8))) short    short8_t;
typedef __attribute__((ext_vector_type(4))) float    float4_t;
typedef __attribute__((ext_vector_type(8))) _Float16 half8_t;

// ============================ small helpers ================================
__device__ __forceinline__ short f2bf(float f) {   // RNE float->bf16 (no NaN inputs here)
  uint32_t u = __float_as_uint(f);
  u += 0x7FFFu + ((u >> 16) & 1u);
  return (short)(u >> 16);
}

// ---- threefry2x32 with key = (0, 42) (jax.random.key(42)) ----
__device__ __forceinline__ void tf2x32(uint32_t x0, uint32_t x1, uint32_t &o0, uint32_t &o1) {
  const uint32_t K0 = 0u;
  const uint32_t K1 = 42u;
  const uint32_t K2 = 0x1BD11BDAu ^ K0 ^ K1;
#define TFR(a) { x0 += x1; x1 = (x1 << a) | (x1 >> (32 - a)); x1 ^= x0; }
  x0 += K0; x1 += K1;
  TFR(13) TFR(15) TFR(26) TFR(6)
  x0 += K1; x1 += K2 + 1u;
  TFR(17) TFR(29) TFR(16) TFR(24)
  x0 += K2; x1 += K0 + 2u;
  TFR(13) TFR(15) TFR(26) TFR(6)
  x0 += K0; x1 += K1 + 3u;
  TFR(17) TFR(29) TFR(16) TFR(24)
  x0 += K1; x1 += K2 + 4u;
  TFR(13) TFR(15) TFR(26) TFR(6)
  x0 += K2; x1 += K0 + 5u;
#undef TFR
  o0 = x0; o1 = x1;
}

// gumbel = -ln(-ln(u)), u = bitcast(bits>>9 | 0x3f800000) - 1, clamped to FLT_MIN.
// t = -ln(u) = -ln(n * 2^-23).  For n near 2^23 (u near 1 -> largest gumbels ->
// dominant softmax weights) fast log cancels catastrophically, so use a series.
__device__ __forceinline__ float gumbel_from_bits(uint32_t bits) {
  const float LN2 = 0.69314718055994531f;
  uint32_t n = bits >> 9;
  float t;
  if (n == 0u) {
    t = 87.3365447504f;                       // -ln(FLT_MIN)
  } else {
    uint32_t m = 8388608u - n;
    if (m < 32768u) {                          // x = m*2^-23 < 2^-8: -ln(1-x) series
      float x = (float)m * 1.1920928955078125e-7f;
      t = x * (1.0f + x * (0.5f + x * (0.3333333333f + x * 0.25f)));
    } else {
      t = (23.0f - __log2f((float)n)) * LN2;   // -ln(n*2^-23)
    }
  }
  return -(__log2f(t) * LN2);
}

__device__ __forceinline__ float gumbel_at(uint32_t e) {
#if GUMBEL_MODE == 1
  uint32_t o0, o1; tf2x32(0u, e, o0, o1);
  return gumbel_from_bits(o0 ^ o1);
#else
  const uint32_t H = 102926336u;               // (4096*50257)/2 = 2048*50257
  uint32_t o0, o1;
  if (e < H) { tf2x32(e, e + H, o0, o1); return gumbel_from_bits(o0); }
  else       { tf2x32(e - H, e, o0, o1); return gumbel_from_bits(o1); }
#endif
}

// ============================ prep kernels =================================
// one block (256 thr) per vocab row: rk[j] = 0.05/max(||E_j||,1e-12), E -> bf16
__global__ void k_prep_e(const float* __restrict__ E, short* __restrict__ Eb,
                         float* __restrict__ rk) {
  int j = blockIdx.x;            // 0..VPAD-1
  int t = threadIdx.x;
  __shared__ float red[4];
  float ssq = 0.f;
  if (j < VOC) {
    if (t < 192) {
      float4_t v = *(const float4_t*)(E + (size_t)j * DEMB + t * 4);
      ssq = v[0]*v[0] + v[1]*v[1] + v[2]*v[2] + v[3]*v[3];
      short4_t b; b[0]=f2bf(v[0]); b[1]=f2bf(v[1]); b[2]=f2bf(v[2]); b[3]=f2bf(v[3]);
      *(short4_t*)(Eb + (size_t)j * DEMB + t * 4) = b;
    }
  } else if (t < 192) {
    short4_t z = {0,0,0,0};
    *(short4_t*)(Eb + (size_t)j * DEMB + t * 4) = z;
  }
  for (int off = 32; off; off >>= 1) ssq += __shfl_xor(ssq, off);
  if ((t & 63) == 0) red[t >> 6] = ssq;
  __syncthreads();
  if (t == 0) {
    float s = red[0] + red[1] + red[2] + red[3];
    rk[j] = (j < VOC) ? (EPS_HALF / fmaxf(sqrtf(s), 1e-12f)) : 0.f;
  }
}

// one block per query: gather E[ids[p]], L2-normalize, write bf16 row of qn
__global__ void k_prep_q(const int* __restrict__ ids, const float* __restrict__ E,
                         short* __restrict__ qn) {
  int p = blockIdx.x;
  int t = threadIdx.x;
  int id = ids[p];
  __shared__ float red[4];
  __shared__ float scale_s;
  float4_t v = {0.f, 0.f, 0.f, 0.f};
  float ssq = 0.f;
  if (t < 192) {
    v = *(const float4_t*)(E + (size_t)id * DEMB + t * 4);
    ssq = v[0]*v[0] + v[1]*v[1] + v[2]*v[2] + v[3]*v[3];
  }
  for (int off = 32; off; off >>= 1) ssq += __shfl_xor(ssq, off);
  if ((t & 63) == 0) red[t >> 6] = ssq;
  __syncthreads();
  if (t == 0) scale_s = 1.0f / fmaxf(sqrtf(red[0]+red[1]+red[2]+red[3]), 1e-12f);
  __syncthreads();
  float sc = scale_s;
  if (t < 192) {
    short4_t b; b[0]=f2bf(v[0]*sc); b[1]=f2bf(v[1]*sc); b[2]=f2bf(v[2]*sc); b[3]=f2bf(v[3]*sc);
    *(short4_t*)(qn + (size_t)p * DEMB + t * 4) = b;
  }
}

// Et[d][key] = Eb[key][d]  (so GEMM2's B operand is row-major-over-K like GEMM1's)
__global__ void k_transpose(const short* __restrict__ Eb, short* __restrict__ Et) {
  int lane = threadIdx.x & 63;
  int dg   = threadIdx.x >> 6;                  // 0..3
  int key  = blockIdx.x * 64 + lane;            // < VPAD
  int d0   = blockIdx.y * 32 + dg * 8;
  short8_t v = *(const short8_t*)(Eb + (size_t)key * DEMB + d0);
#pragma unroll
  for (int q = 0; q < 8; ++q)
    Et[(size_t)(d0 + q) * VPAD + key] = v[q];
}

// ============================ GEMM plumbing ================================
// 128x128 tile, BK=64, 256 threads (4 waves, 2x2 quadrants of 64x64),
// 16x16x32 bf16 MFMA, XOR-swizzled LDS ( G4 / T2-style, read==write swizzle ).
__device__ __forceinline__ int swz(int row, int byte) {
  return (row << 7) + (byte ^ ((row & 7) << 4));
}

__device__ __forceinline__ void stage_bf16(short* L, const short* __restrict__ g,
                                           int row0, int rowcap, long rowstride,
                                           long col0, int tid) {
  int row = tid >> 1;
  int ch  = (tid & 1) * 64;                      // byte half of the 128B row
  long grow = row0 + row; if (grow > rowcap) grow = rowcap;
  const short8_t* src = (const short8_t*)(g + grow * rowstride + col0 + (ch >> 1));
#pragma unroll
  for (int i = 0; i < 4; ++i) {
    short8_t v = src[i];
    *(short8_t*)(L + (swz(row, ch + i * 16) >> 1)) = v;
  }
}

// fragment: 8 bf16 along K; groups of 4 at k=4g.. and k=16+4g.. (consistent A/B
// mapping => any true-HW within-K permutation cancels inside the MFMA dot)
__device__ __forceinline__ short8_t ldfrag(const short* L, int row, int kbyte) {
  int a0 = swz(row, kbyte) >> 1;
  int a1 = swz(row, kbyte + 32) >> 1;
  short4_t lo = *(const short4_t*)(L + a0);
  short4_t hi = *(const short4_t*)(L + a1);
  short8_t f;
  f[0]=lo[0]; f[1]=lo[1]; f[2]=lo[2]; f[3]=lo[3];
  f[4]=hi[0]; f[5]=hi[1]; f[6]=hi[2]; f[7]=hi[3];
  return f;
}

// ---- GEMM1: logits[p][jc] = (qn_p . E_j) * rk[j] + gumbel(p*VOC+j)  (fp16) ----
__global__ __launch_bounds__(256) void k_gemm1(
    const short* __restrict__ qn, const short* __restrict__ Eb,
    const float* __restrict__ rk, _Float16* __restrict__ logits,
    int c0, int KC) {
  __shared__ short lA[128 * 64];
  __shared__ short lB[128 * 64];
  int tid = threadIdx.x, lane = tid & 63;
  int wv = tid >> 6, wr = wv >> 1, wc = wv & 1;
  int rowbase = blockIdx.x * 128;
  int colbase = blockIdx.y * 128;               // within chunk
  float4_t acc[4][4];
  float4_t zero = {0.f, 0.f, 0.f, 0.f};
#pragma unroll
  for (int mt = 0; mt < 4; ++mt)
#pragma unroll
    for (int nt = 0; nt < 4; ++nt) acc[mt][nt] = zero;

  for (int kt = 0; kt < DEMB / 64; ++kt) {
    __syncthreads();
    stage_bf16(lA, qn, rowbase,      NQ - 1,   DEMB, kt * 64, tid);
    stage_bf16(lB, Eb, c0 + colbase, VPAD - 1, DEMB, kt * 64, tid);
    __syncthreads();
#pragma unroll
    for (int ks = 0; ks < 2; ++ks) {
      int kb = ks * 64 + (lane >> 4) * 8;
      short8_t a[4], b[4];
#pragma unroll
      for (int mt = 0; mt < 4; ++mt) a[mt] = ldfrag(lA, wr * 64 + mt * 16 + (lane & 15), kb);
#pragma unroll
      for (int nt = 0; nt < 4; ++nt) b[nt] = ldfrag(lB, wc * 64 + nt * 16 + (lane & 15), kb);
#pragma unroll
      for (int mt = 0; mt < 4; ++mt)
#pragma unroll
        for (int nt = 0; nt < 4; ++nt)
          acc[mt][nt] = __builtin_amdgcn_mfma_f32_16x16x32_bf16(a[mt], b[nt], acc[mt][nt], 0, 0, 0);
    }
  }
  // epilogue: scale, add gumbel, store fp16  (C/D: col=lane&15, row=(lane>>4)*4+reg)
#pragma unroll
  for (int mt = 0; mt < 4; ++mt) {
    int prow = rowbase + wr * 64 + mt * 16 + ((lane >> 4) << 2);
#pragma unroll
    for (int nt = 0; nt < 4; ++nt) {
      int jc = colbase + wc * 64 + nt * 16 + (lane & 15);
      int j  = c0 + jc;
      float rkj = (j < VOC) ? rk[j] : 0.f;
#pragma unroll
      for (int r = 0; r < 4; ++r) {
        int p = prow + r;
        float s;
        if (j < VOC) s = acc[mt][nt][r] * rkj + gumbel_at((uint32_t)p * (uint32_t)VOC + (uint32_t)j);
        else         s = -30000.f;               // finite sentinel (fp16-safe, exp->0)
        logits[(size_t)p * KC + jc] = (_Float16)s;
      }
    }
  }
}

// ---- per-row chunk stats + flash-style running (m,l) update ----
template<int NC>
__global__ __launch_bounds__(256) void k_stats(
    const _Float16* __restrict__ logits, int KC, int chunk,
    float* __restrict__ m_run, float* __restrict__ l_run,
    float* __restrict__ m_use, float* __restrict__ oscale) {
  int row = blockIdx.x, t = threadIdx.x;
  const half8_t* src = (const half8_t*)(logits + (size_t)row * KC);
  half8_t v[NC];
  float m = -1e30f;
#pragma unroll
  for (int i = 0; i < NC; ++i) {
    v[i] = src[i * 256 + t];
#pragma unroll
    for (int j = 0; j < 8; ++j) m = fmaxf(m, (float)v[i][j]);
  }
  float l = 0.f;
#pragma unroll
  for (int i = 0; i < NC; ++i)
#pragma unroll
    for (int j = 0; j < 8; ++j) l += __expf((float)v[i][j] - m);
  for (int off = 32; off; off >>= 1) {
    float m2 = __shfl_xor(m, off), l2 = __shfl_xor(l, off);
    float M = fmaxf(m, m2);
    l = l * __expf(m - M) + l2 * __expf(m2 - M);
    m = M;
  }
  __shared__ float sm[4], sl[4];
  if ((t & 63) == 0) { sm[t >> 6] = m; sl[t >> 6] = l; }
  __syncthreads();
  if (t == 0) {
    float M = fmaxf(fmaxf(sm[0], sm[1]), fmaxf(sm[2], sm[3]));
    float L = sl[0]*__expf(sm[0]-M) + sl[1]*__expf(sm[1]-M)
            + sl[2]*__expf(sm[2]-M) + sl[3]*__expf(sm[3]-M);
    if (chunk == 0) {
      m_run[row] = M; l_run[row] = L; m_use[row] = M; oscale[row] = 0.f; // 0 also zero-inits O
    } else {
      float mo = m_run[row], lo = l_run[row];
      float Mn = fmaxf(mo, M);
      l_run[row] = lo * __expf(mo - Mn) + L * __expf(M - Mn);
      m_run[row] = Mn; m_use[row] = Mn;
      oscale[row] = __expf(mo - Mn);
    }
  }
}

__global__ void k_scaleO(float* __restrict__ O, const float* __restrict__ oscale) {
  int idx = blockIdx.x * 256 + threadIdx.x;      // float4 index
  float s = oscale[idx / 192];                   // 192 float4 per row
  float4_t v = ((const float4_t*)O)[idx];
  v[0]*=s; v[1]*=s; v[2]*=s; v[3]*=s;
  ((float4_t*)O)[idx] = v;
}

// ---- GEMM2: O[p][d] += sum_k exp(logit[p][k]-m_use[p]) * E[k][d]  (split-K atomics) ----
__global__ __launch_bounds__(256) void k_gemm2(
    const _Float16* __restrict__ logits, const short* __restrict__ Et,
    const float* __restrict__ m_use, float* __restrict__ O,
    int c0, int KC, int kseg) {
  __shared__ short lA[128 * 64];
  __shared__ short lB[128 * 64];
  int tid = threadIdx.x, lane = tid & 63;
  int wv = tid >> 6, wr = wv >> 1, wc = wv & 1;
  int rowbase = blockIdx.x * 128;
  int colbase = blockIdx.y * 128;                // output dim (<768)
  int kbase   = blockIdx.z * kseg;               // within chunk
  float4_t acc[4][4];
  float4_t zero = {0.f, 0.f, 0.f, 0.f};
#pragma unroll
  for (int mt = 0; mt < 4; ++mt)
#pragma unroll
    for (int nt = 0; nt < 4; ++nt) acc[mt][nt] = zero;

  int srow = tid >> 1;
  float mrow = m_use[rowbase + srow];

  for (int kt = 0; kt < kseg / 64; ++kt) {
    __syncthreads();
    { // A tile: P = exp(logit - m) computed in-staging, cast bf16
      const half8_t* src = (const half8_t*)(logits + (size_t)(rowbase + srow) * KC
                                            + kbase + kt * 64 + (tid & 1) * 32);
#pragma unroll
      for (int i = 0; i < 4; ++i) {
        half8_t h = src[i];
        short8_t pv;
#pragma unroll
        for (int j = 0; j < 8; ++j) pv[j] = f2bf(__expf((float)h[j] - mrow));
        *(short8_t*)(lA + (swz(srow, (tid & 1) * 64 + i * 16) >> 1)) = pv;
      }
    }
    stage_bf16(lB, Et, colbase, DEMB - 1, VPAD, (long)c0 + kbase + kt * 64, tid);
    __syncthreads();
#pragma unroll
    for (int ks = 0; ks < 2; ++ks) {
      int kb = ks * 64 + (lane >> 4) * 8;
      short8_t a[4], b[4];
#pragma unroll
      for (int mt = 0; mt < 4; ++mt) a[mt] = ldfrag(lA, wr * 64 + mt * 16 + (lane & 15), kb);
#pragma unroll
      for (int nt = 0; nt < 4; ++nt) b[nt] = ldfrag(lB, wc * 64 + nt * 16 + (lane & 15), kb);
#pragma unroll
      for (int mt = 0; mt < 4; ++mt)
#pragma unroll
        for (int nt = 0; nt < 4; ++nt)
          acc[mt][nt] = __builtin_amdgcn_mfma_f32_16x16x32_bf16(a[mt], b[nt], acc[mt][nt], 0, 0, 0);
    }
  }
#pragma unroll
  for (int mt = 0; mt < 4; ++mt)
#pragma unroll
    for (int nt = 0; nt < 4; ++nt) {
      int d = colbase + wc * 64 + nt * 16 + (lane & 15);
#pragma unroll
      for (int r = 0; r < 4; ++r) {
        int p = rowbase + wr * 64 + mt * 16 + ((lane >> 4) << 2) + r;
        unsafeAtomicAdd(&O[(size_t)p * DEMB + d], acc[mt][nt][r]);
      }
    }
}

__global__ void k_finalize(const float* __restrict__ O, const float* __restrict__ l_run,
                           float* __restrict__ out) {
  int idx = blockIdx.x * 256 + threadIdx.x;      // float4 index
  float inv = 1.0f / l_run[idx / 192];
  float4_t v = ((const float4_t*)O)[idx];
  v[0]*=inv; v[1]*=inv; v[2]*=inv; v[3]*=inv;
  ((float4_t*)out)[idx] = v;
}

// ============================ host launcher ================================
extern "C" void kernel_launch(void* const* d_in, const int* in_sizes, int n_in,
                              void* d_out, int out_size, void* d_ws, size_t ws_size,
                              hipStream_t stream) {
  (void)in_sizes; (void)n_in; (void)out_size;
  const int*   ids = (const int*)d_in[0];
  const float* E   = (const float*)d_in[1];
  float*       out = (float*)d_out;

  char* w = (char*)d_ws;
  short* Eb = (short*)w;      w += (size_t)VPAD * DEMB * 2;   // 77.3 MB
  short* Et = (short*)w;      w += (size_t)DEMB * VPAD * 2;   // 77.3 MB
  short* qn = (short*)w;      w += (size_t)NQ * DEMB * 2;     // 6.3 MB
  float* O  = (float*)w;      w += (size_t)NQ * DEMB * 4;     // 12.6 MB
  float* rk = (float*)w;      w += (size_t)VPAD * 4;
  float* m_run  = (float*)w;  w += NQ * 4;
  float* l_run  = (float*)w;  w += NQ * 4;
  float* m_use  = (float*)w;  w += NQ * 4;
  float* oscale = (float*)w;  w += NQ * 4;
  _Float16* logits = (_Float16*)w;
  size_t fixed = (size_t)(w - (char*)d_ws);

  int KC = 2048;                                             // logits chunk width
  if      (fixed + (size_t)NQ * 8192 * 2 <= ws_size) KC = 8192;
  else if (fixed + (size_t)NQ * 4096 * 2 <= ws_size) KC = 4096;
  int KSPLIT = (KC == 8192) ? 4 : (KC == 4096 ? 2 : 1);
  int chunks = (VOC + KC - 1) / KC;

  k_prep_e<<<VPAD, 256, 0, stream>>>(E, Eb, rk);
  k_prep_q<<<NQ, 256, 0, stream>>>(ids, E, qn);
  k_transpose<<<dim3(VPAD / 64, DEMB / 32), 256, 0, stream>>>(Eb, Et);

  for (int c = 0; c < chunks; ++c) {
    int c0 = c * KC;
    k_gemm1<<<dim3(NQ / 128, KC / 128), 256, 0, stream>>>(qn, Eb, rk, logits, c0, KC);
    if (KC == 8192)      k_stats<4><<<NQ, 256, 0, stream>>>(logits, KC, c, m_run, l_run, m_use, oscale);
    else if (KC == 4096) k_stats<2><<<NQ, 256, 0, stream>>>(logits, KC, c, m_run, l_run, m_use, oscale);
    else                 k_stats<1><<<NQ, 256, 0, stream>>>(logits, KC, c, m_run, l_run, m_use, oscale);
    k_scaleO<<<(NQ * DEMB / 4) / 256, 256, 0, stream>>>(O, oscale);
    k_gemm2<<<dim3(NQ / 128, DEMB / 128, KSPLIT), 256, 0, stream>>>(logits, Et, m_use, O,
                                                                    c0, KC, KC / KSPLIT);
  }
  k_finalize<<<(NQ * DEMB / 4) / 256, 256, 0, stream>>>(O, l_run, out);
}

// Round 2
// 1483.649 us; speedup vs baseline: 1.4210x; 1.4210x over previous
//
#include <hip/hip_runtime.h>
#include <stdint.h>

// ============================ problem constants ============================
constexpr int VOC  = 50257;
constexpr int VPAD = 50304;          // VOC padded up to a multiple of 128
constexpr int DEMB = 768;
constexpr int NQ   = 4096;           // B*T
constexpr float EPS_HALF = 0.05f;    // EPSILON / 2
constexpr float MFIX = 16.0f;        // fixed softmax max: logit = sim*0.05 + gumbel < 16 always
                                     // (gumbel <= -ln(2^-23) = 15.9424, |sim*0.05| <= 0.05)

// 1 = jax threefry_partitionable (default in modern JAX): bits = o0^o1 of (0, idx)
#define GUMBEL_MODE 1

typedef __attribute__((ext_vector_type(4))) short    short4_t;
typedef __attribute__((ext_vector_type(8))) short    short8_t;
typedef __attribute__((ext_vector_type(4))) float    float4_t;

// ============================ small helpers ================================
__device__ __forceinline__ short f2bf(float f) {   // RNE float->bf16
  uint32_t u = __float_as_uint(f);
  u += 0x7FFFu + ((u >> 16) & 1u);
  return (short)(u >> 16);
}
__device__ __forceinline__ float bf2f(short b) {
  return __uint_as_float(((uint32_t)(uint16_t)b) << 16);
}

// ---- threefry2x32 with key = (0, 42) (jax.random.key(42)) ----
__device__ __forceinline__ void tf2x32(uint32_t x0, uint32_t x1, uint32_t &o0, uint32_t &o1) {
  const uint32_t K0 = 0u;
  const uint32_t K1 = 42u;
  const uint32_t K2 = 0x1BD11BDAu ^ K0 ^ K1;
#define TFR(a) { x0 += x1; x1 = (x1 << a) | (x1 >> (32 - a)); x1 ^= x0; }
  x0 += K0; x1 += K1;
  TFR(13) TFR(15) TFR(26) TFR(6)
  x0 += K1; x1 += K2 + 1u;
  TFR(17) TFR(29) TFR(16) TFR(24)
  x0 += K2; x1 += K0 + 2u;
  TFR(13) TFR(15) TFR(26) TFR(6)
  x0 += K0; x1 += K1 + 3u;
  TFR(17) TFR(29) TFR(16) TFR(24)
  x0 += K1; x1 += K2 + 4u;
  TFR(13) TFR(15) TFR(26) TFR(6)
  x0 += K2; x1 += K0 + 5u;
#undef TFR
  o0 = x0; o1 = x1;
}

// gumbel = -ln(-ln(u)), u = n*2^-23 (n = bits>>9), clamped to FLT_MIN.
// For u near 1 (largest gumbels -> dominant softmax weights) use a -ln(1-x) series
// to avoid catastrophic cancellation in the fast log.
__device__ __forceinline__ float gumbel_from_bits(uint32_t bits) {
  const float LN2 = 0.69314718055994531f;
  uint32_t n = bits >> 9;
  float t;
  if (n == 0u) {
    t = 87.3365447504f;                       // -ln(FLT_MIN)
  } else {
    uint32_t m = 8388608u - n;
    if (m < 32768u) {                          // x = m*2^-23 < 2^-8
      float x = (float)m * 1.1920928955078125e-7f;
      t = x * (1.0f + x * (0.5f + x * (0.3333333333f + x * 0.25f)));
    } else {
      t = (23.0f - __log2f((float)n)) * LN2;   // -ln(n*2^-23)
    }
  }
  return -(__log2f(t) * LN2);
}

__device__ __forceinline__ float gumbel_at(uint32_t e) {
#if GUMBEL_MODE == 1
  uint32_t o0, o1; tf2x32(0u, e, o0, o1);
  return gumbel_from_bits(o0 ^ o1);
#else
  const uint32_t H = 102926336u;
  uint32_t o0, o1;
  if (e < H) { tf2x32(e, e + H, o0, o1); return gumbel_from_bits(o0); }
  else       { tf2x32(e - H, e, o0, o1); return gumbel_from_bits(o1); }
#endif
}

// ============================ prep kernels =================================
__global__ void k_prep_e(const float* __restrict__ E, short* __restrict__ Eb,
                         float* __restrict__ rk) {
  int j = blockIdx.x;            // 0..VPAD-1
  int t = threadIdx.x;
  __shared__ float red[4];
  float ssq = 0.f;
  if (j < VOC) {
    if (t < 192) {
      float4_t v = *(const float4_t*)(E + (size_t)j * DEMB + t * 4);
      ssq = v[0]*v[0] + v[1]*v[1] + v[2]*v[2] + v[3]*v[3];
      short4_t b; b[0]=f2bf(v[0]); b[1]=f2bf(v[1]); b[2]=f2bf(v[2]); b[3]=f2bf(v[3]);
      *(short4_t*)(Eb + (size_t)j * DEMB + t * 4) = b;
    }
  } else if (t < 192) {
    short4_t z = {0,0,0,0};
    *(short4_t*)(Eb + (size_t)j * DEMB + t * 4) = z;
  }
  for (int off = 32; off; off >>= 1) ssq += __shfl_xor(ssq, off);
  if ((t & 63) == 0) red[t >> 6] = ssq;
  __syncthreads();
  if (t == 0) {
    float s = red[0] + red[1] + red[2] + red[3];
    rk[j] = (j < VOC) ? (EPS_HALF / fmaxf(sqrtf(s), 1e-12f)) : 0.f;
  }
}

__global__ void k_prep_q(const int* __restrict__ ids, const float* __restrict__ E,
                         short* __restrict__ qn) {
  int p = blockIdx.x;
  int t = threadIdx.x;
  int id = ids[p];
  __shared__ float red[4];
  __shared__ float scale_s;
  float4_t v = {0.f, 0.f, 0.f, 0.f};
  float ssq = 0.f;
  if (t < 192) {
    v = *(const float4_t*)(E + (size_t)id * DEMB + t * 4);
    ssq = v[0]*v[0] + v[1]*v[1] + v[2]*v[2] + v[3]*v[3];
  }
  for (int off = 32; off; off >>= 1) ssq += __shfl_xor(ssq, off);
  if ((t & 63) == 0) red[t >> 6] = ssq;
  __syncthreads();
  if (t == 0) scale_s = 1.0f / fmaxf(sqrtf(red[0]+red[1]+red[2]+red[3]), 1e-12f);
  __syncthreads();
  float sc = scale_s;
  if (t < 192) {
    short4_t b; b[0]=f2bf(v[0]*sc); b[1]=f2bf(v[1]*sc); b[2]=f2bf(v[2]*sc); b[3]=f2bf(v[3]*sc);
    *(short4_t*)(qn + (size_t)p * DEMB + t * 4) = b;
  }
}

// Et[d][key] = Eb[key][d]
__global__ void k_transpose(const short* __restrict__ Eb, short* __restrict__ Et) {
  int lane = threadIdx.x & 63;
  int dg   = threadIdx.x >> 6;
  int key  = blockIdx.x * 64 + lane;
  int d0   = blockIdx.y * 32 + dg * 8;
  short8_t v = *(const short8_t*)(Eb + (size_t)key * DEMB + d0);
#pragma unroll
  for (int q = 0; q < 8; ++q)
    Et[(size_t)(d0 + q) * VPAD + key] = v[q];
}

__global__ void k_zero(float* __restrict__ O, float* __restrict__ lsum) {
  int idx = blockIdx.x * 256 + threadIdx.x;      // float4 index over O
  if (idx < NQ) lsum[idx] = 0.f;
  float4_t z = {0.f, 0.f, 0.f, 0.f};
  ((float4_t*)O)[idx] = z;
}

// ============================ GEMM plumbing ================================
// 128x128 tile, BK=64, 256 threads (4 waves, 2x2 quadrants of 64x64),
// 16x16x32 bf16 MFMA, XOR-swizzled LDS (read swizzle == write swizzle).
__device__ __forceinline__ int swz(int row, int byte) {
  return (row << 7) + (byte ^ ((row & 7) << 4));
}

__device__ __forceinline__ void stage_bf16(short* L, const short* __restrict__ g,
                                           int row0, int rowcap, long rowstride,
                                           long col0, int tid) {
  int row = tid >> 1;
  int ch  = (tid & 1) * 64;
  long grow = row0 + row; if (grow > rowcap) grow = rowcap;
  const short8_t* src = (const short8_t*)(g + grow * rowstride + col0 + (ch >> 1));
#pragma unroll
  for (int i = 0; i < 4; ++i) {
    short8_t v = src[i];
    *(short8_t*)(L + (swz(row, ch + i * 16) >> 1)) = v;
  }
}

// single ds_read_b128 fragment: reg r of k-group g holds k = ks*32 + 8g + r.
// A and B use the identical mapping, so the within-K permutation cancels in the dot.
__device__ __forceinline__ short8_t ldfrag(const short* L, int row, int kbyte) {
  return *(const short8_t*)(L + (swz(row, kbyte) >> 1));
}

// ---- GEMM1: P[p][jc] = exp(sim*rk + gumbel - 16)  (bf16) + row-sum atomics ----
__global__ __launch_bounds__(256) void k_gemm1(
    const short* __restrict__ qn, const short* __restrict__ Eb,
    const float* __restrict__ rk, short* __restrict__ P,
    float* __restrict__ lsum, int c0, int KC) {
  __shared__ short lA[128 * 64];
  __shared__ short lB[128 * 64];
  int tid = threadIdx.x, lane = tid & 63;
  int wv = tid >> 6, wr = wv >> 1, wc = wv & 1;
  int rowbase = blockIdx.x * 128;
  int colbase = blockIdx.y * 128;
  float4_t acc[4][4];
  float4_t zero = {0.f, 0.f, 0.f, 0.f};
#pragma unroll
  for (int mt = 0; mt < 4; ++mt)
#pragma unroll
    for (int nt = 0; nt < 4; ++nt) acc[mt][nt] = zero;

  for (int kt = 0; kt < DEMB / 64; ++kt) {
    __syncthreads();
    stage_bf16(lA, qn, rowbase,      NQ - 1,   DEMB, kt * 64, tid);
    stage_bf16(lB, Eb, c0 + colbase, VPAD - 1, DEMB, kt * 64, tid);
    __syncthreads();
#pragma unroll
    for (int ks = 0; ks < 2; ++ks) {
      int kb = ks * 64 + (lane >> 4) * 16;
      short8_t a[4], b[4];
#pragma unroll
      for (int mt = 0; mt < 4; ++mt) a[mt] = ldfrag(lA, wr * 64 + mt * 16 + (lane & 15), kb);
#pragma unroll
      for (int nt = 0; nt < 4; ++nt) b[nt] = ldfrag(lB, wc * 64 + nt * 16 + (lane & 15), kb);
#pragma unroll
      for (int mt = 0; mt < 4; ++mt)
#pragma unroll
        for (int nt = 0; nt < 4; ++nt)
          acc[mt][nt] = __builtin_amdgcn_mfma_f32_16x16x32_bf16(a[mt], b[nt], acc[mt][nt], 0, 0, 0);
    }
  }
  // epilogue: P = exp(sim*rk + gumbel - 16), store bf16, row-sum -> atomics
  // C/D layout: col = lane&15, row = (lane>>4)*4 + reg
#pragma unroll
  for (int mt = 0; mt < 4; ++mt) {
    int prow = rowbase + wr * 64 + mt * 16 + ((lane >> 4) << 2);
    float rowsum[4] = {0.f, 0.f, 0.f, 0.f};
#pragma unroll
    for (int nt = 0; nt < 4; ++nt) {
      int jc = colbase + wc * 64 + nt * 16 + (lane & 15);
      int j  = c0 + jc;
      bool ok = j < VOC;
      float rkj = ok ? rk[j] : 0.f;
#pragma unroll
      for (int r = 0; r < 4; ++r) {
        int p = prow + r;
        short pb = 0;
        if (ok) {
          float s = acc[mt][nt][r] * rkj
                  + gumbel_at((uint32_t)p * (uint32_t)VOC + (uint32_t)j) - MFIX;
          pb = f2bf(__expf(s));
          rowsum[r] += bf2f(pb);               // sum exactly what gemm2 will consume
        }
        P[(size_t)p * KC + jc] = pb;
      }
    }
#pragma unroll
    for (int r = 0; r < 4; ++r) {
      float s = rowsum[r];
      s += __shfl_xor(s, 1); s += __shfl_xor(s, 2);
      s += __shfl_xor(s, 4); s += __shfl_xor(s, 8);
      if ((lane & 15) == 0) unsafeAtomicAdd(&lsum[prow + r], s);
    }
  }
}

// ---- GEMM2: O[p][d] += sum_k P[p][k] * Et[d][k]  (pure bf16 GEMM, split-K atomics) ----
__global__ __launch_bounds__(256) void k_gemm2(
    const short* __restrict__ P, const short* __restrict__ Et,
    float* __restrict__ O, int c0, int KC, int kseg) {
  __shared__ short lA[128 * 64];
  __shared__ short lB[128 * 64];
  int tid = threadIdx.x, lane = tid & 63;
  int wv = tid >> 6, wr = wv >> 1, wc = wv & 1;
  int rowbase = blockIdx.x * 128;
  int colbase = blockIdx.y * 128;                // output dim (<768)
  int kbase   = blockIdx.z * kseg;               // within chunk
  float4_t acc[4][4];
  float4_t zero = {0.f, 0.f, 0.f, 0.f};
#pragma unroll
  for (int mt = 0; mt < 4; ++mt)
#pragma unroll
    for (int nt = 0; nt < 4; ++nt) acc[mt][nt] = zero;

  for (int kt = 0; kt < kseg / 64; ++kt) {
    __syncthreads();
    stage_bf16(lA, P,  rowbase, NQ - 1,   KC,   kbase + kt * 64, tid);
    stage_bf16(lB, Et, colbase, DEMB - 1, VPAD, (long)c0 + kbase + kt * 64, tid);
    __syncthreads();
#pragma unroll
    for (int ks = 0; ks < 2; ++ks) {
      int kb = ks * 64 + (lane >> 4) * 16;
      short8_t a[4], b[4];
#pragma unroll
      for (int mt = 0; mt < 4; ++mt) a[mt] = ldfrag(lA, wr * 64 + mt * 16 + (lane & 15), kb);
#pragma unroll
      for (int nt = 0; nt < 4; ++nt) b[nt] = ldfrag(lB, wc * 64 + nt * 16 + (lane & 15), kb);
#pragma unroll
      for (int mt = 0; mt < 4; ++mt)
#pragma unroll
        for (int nt = 0; nt < 4; ++nt)
          acc[mt][nt] = __builtin_amdgcn_mfma_f32_16x16x32_bf16(a[mt], b[nt], acc[mt][nt], 0, 0, 0);
    }
  }
#pragma unroll
  for (int mt = 0; mt < 4; ++mt)
#pragma unroll
    for (int nt = 0; nt < 4; ++nt) {
      int d = colbase + wc * 64 + nt * 16 + (lane & 15);
#pragma unroll
      for (int r = 0; r < 4; ++r) {
        int p = rowbase + wr * 64 + mt * 16 + ((lane >> 4) << 2) + r;
        unsafeAtomicAdd(&O[(size_t)p * DEMB + d], acc[mt][nt][r]);
      }
    }
}

__global__ void k_finalize(const float* __restrict__ O, const float* __restrict__ lsum,
                           float* __restrict__ out) {
  int idx = blockIdx.x * 256 + threadIdx.x;      // float4 index
  float inv = 1.0f / lsum[idx / 192];            // 192 float4 per row
  float4_t v = ((const float4_t*)O)[idx];
  v[0]*=inv; v[1]*=inv; v[2]*=inv; v[3]*=inv;
  ((float4_t*)out)[idx] = v;
}

// ============================ host launcher ================================
extern "C" void kernel_launch(void* const* d_in, const int* in_sizes, int n_in,
                              void* d_out, int out_size, void* d_ws, size_t ws_size,
                              hipStream_t stream) {
  (void)in_sizes; (void)n_in; (void)out_size;
  const int*   ids = (const int*)d_in[0];
  const float* E   = (const float*)d_in[1];
  float*       out = (float*)d_out;

  char* w = (char*)d_ws;
  short* Eb = (short*)w;      w += (size_t)VPAD * DEMB * 2;   // 77.3 MB
  short* Et = (short*)w;      w += (size_t)DEMB * VPAD * 2;   // 77.3 MB
  short* qn = (short*)w;      w += (size_t)NQ * DEMB * 2;     // 6.3 MB
  float* O  = (float*)w;      w += (size_t)NQ * DEMB * 4;     // 12.6 MB
  float* rk = (float*)w;      w += (size_t)VPAD * 4;
  float* lsum = (float*)w;    w += NQ * 4;
  short* P  = (short*)w;                                      // bf16 P chunk
  size_t fixed = (size_t)(w - (char*)d_ws);

  int KC = 2048;
  if      (fixed + (size_t)NQ * 8192 * 2 <= ws_size) KC = 8192;
  else if (fixed + (size_t)NQ * 4096 * 2 <= ws_size) KC = 4096;
  int chunks = (VPAD + KC - 1) / KC;

  k_zero<<<(NQ * DEMB / 4) / 256, 256, 0, stream>>>(O, lsum);
  k_prep_e<<<VPAD, 256, 0, stream>>>(E, Eb, rk);
  k_prep_q<<<NQ, 256, 0, stream>>>(ids, E, qn);
  k_transpose<<<dim3(VPAD / 64, DEMB / 32), 256, 0, stream>>>(Eb, Et);

  for (int c = 0; c < chunks; ++c) {
    int c0 = c * KC;
    int KCeff = VPAD - c0; if (KCeff > KC) KCeff = KC;        // multiple of 128
    k_gemm1<<<dim3(NQ / 128, KCeff / 128), 256, 0, stream>>>(qn, Eb, rk, P, lsum, c0, KC);
    int KS = 4;
    while (KS > 1 && (KCeff % (KS * 64)) != 0) KS >>= 1;
    k_gemm2<<<dim3(NQ / 128, DEMB / 128, KS), 256, 0, stream>>>(P, Et, O, c0, KC, KCeff / KS);
  }
  k_finalize<<<(NQ * DEMB / 4) / 256, 256, 0, stream>>>(O, lsum, out);
}